// Round 5
// baseline (82.768 us; speedup 1.0000x reference)
//
#include <hip/hip_runtime.h>

// Geometry fixed by setup_inputs: b=16, n=32, h=w=256.
#define B 16
#define N 32
#define HW 65536
#define CHUNK 2048            // elements of (h,w) per block
#define CPB (HW / CHUNK)      // 32 chunks per b
#define NBLK (B * CPB)        // 512 blocks
#define PAIRS (B * N)         // 512
#define F4 (CHUNK / 4 / 256)  // float4 per thread = 2
#define EPS 1e-6f

// Structure: block = (b, chunk); pd/gt chunk held in registers; the 32 masks
// streamed with a 3-deep rotating register pipeline (forces loads in flight).
// Two-kernel reduce — NO cross-workgroup atomics/fences (R2/R3: any per-block
// acquire/release = chip-wide L2 flush, 4.5x regression).

__global__ __launch_bounds__(256, 1) void iou_partial_kernel(
    const float* __restrict__ pd, const float* __restrict__ gt,
    const int* __restrict__ pdm, const int* __restrict__ gtm,
    float2* __restrict__ ws)
{
    const int blk   = blockIdx.x;     // 0..511
    const int b     = blk >> 5;       // / CPB
    const int chunk = blk & 31;       // % CPB
    const int t     = threadIdx.x;
    const int base  = chunk * CHUNK;

    const float4* __restrict__ pdp = (const float4*)(pd + (size_t)b * HW + base);
    const float4* __restrict__ gtp = (const float4*)(gt + (size_t)b * HW + base);
    const int4*   __restrict__ pmp = (const int4*)(pdm + ((size_t)b * N) * HW + base);
    const int4*   __restrict__ gmp = (const int4*)(gtm + ((size_t)b * N) * HW + base);

    // pd/gt chunk -> registers, loaded ONCE for all 32 n
    float4 p[F4], g[F4];
    #pragma unroll
    for (int u = 0; u < F4; ++u) {
        p[u] = pdp[u * 256 + t];
        g[u] = gtp[u * 256 + t];
    }

    float accI[N], accU[N];

    // 3-deep rotating mask pipeline (fully unrolled -> all static indices)
    int4 pmB[3][F4], gmB[3][F4];
#define LOADM(slot, n)                                          \
    {   const int _o = (n) * (HW / 4);                          \
        _Pragma("unroll")                                       \
        for (int u = 0; u < F4; ++u) {                          \
            pmB[slot][u] = pmp[_o + u * 256 + t];               \
            gmB[slot][u] = gmp[_o + u * 256 + t];               \
        }                                                       \
    }

    LOADM(0, 0) LOADM(1, 1) LOADM(2, 2)

    #pragma unroll
    for (int n = 0; n < N; ++n) {
        const int cur = n % 3;        // constant after unroll
        float I = 0.0f, U = 0.0f;
        #pragma unroll
        for (int u = 0; u < F4; ++u) {
            const int4 pm = pmB[cur][u];
            const int4 gm = gmB[cur][u];
            I += (pm.x & gm.x) ? p[u].x : 0.0f;
            I += (pm.y & gm.y) ? p[u].y : 0.0f;
            I += (pm.z & gm.z) ? p[u].z : 0.0f;
            I += (pm.w & gm.w) ? p[u].w : 0.0f;

            U += (gm.x ? g[u].x : 0.0f) + ((pm.x & ~gm.x) ? p[u].x : 0.0f);
            U += (gm.y ? g[u].y : 0.0f) + ((pm.y & ~gm.y) ? p[u].y : 0.0f);
            U += (gm.z ? g[u].z : 0.0f) + ((pm.z & ~gm.z) ? p[u].z : 0.0f);
            U += (gm.w ? g[u].w : 0.0f) + ((pm.w & ~gm.w) ? p[u].w : 0.0f);
        }
        accI[n] = I;
        accU[n] = U;
        if (n + 3 < N) LOADM(cur, n + 3)   // refill consumed slot
    }
#undef LOADM

    // per-n wave64 butterfly, then cross-wave via LDS
    __shared__ float sI[4][N], sU[4][N];
    const int wave = t >> 6, lane = t & 63;
    #pragma unroll
    for (int n = 0; n < N; ++n) {
        float I = accI[n], U = accU[n];
        #pragma unroll
        for (int o = 32; o > 0; o >>= 1) {
            I += __shfl_down(I, o, 64);
            U += __shfl_down(U, o, 64);
        }
        if (lane == 0) { sI[wave][n] = I; sU[wave][n] = U; }
    }
    __syncthreads();
    if (t < N) {
        const float I = sI[0][t] + sI[1][t] + sI[2][t] + sI[3][t];
        const float U = sU[0][t] + sU[1][t] + sU[2][t] + sU[3][t];
        ws[((size_t)b * N + t) * CPB + chunk] = make_float2(I, U);
    }
}

__global__ __launch_bounds__(512) void iou_final_kernel(
    const float2* __restrict__ ws, float* __restrict__ out)
{
    const int t = threadIdx.x;   // one thread per (b,n) pair
    const float4* __restrict__ w4 = (const float4*)(ws + (size_t)t * CPB);
    float I = 0.0f, U = 0.0f;
    #pragma unroll
    for (int c = 0; c < CPB / 2; ++c) {   // 16 float4 = 32 float2
        const float4 v = w4[c];
        I += v.x + v.z;
        U += v.y + v.w;
    }
    float loss = I / (U + EPS);

    #pragma unroll
    for (int o = 32; o > 0; o >>= 1)
        loss += __shfl_down(loss, o, 64);

    __shared__ float s[8];
    const int wave = t >> 6, lane = t & 63;
    if (lane == 0) s[wave] = loss;
    __syncthreads();
    if (t == 0) {
        float sum = 0.0f;
        #pragma unroll
        for (int w = 0; w < 8; ++w) sum += s[w];
        out[0] = 1.0f - sum / (float)PAIRS;
    }
}

extern "C" void kernel_launch(void* const* d_in, const int* in_sizes, int n_in,
                              void* d_out, int out_size, void* d_ws, size_t ws_size,
                              hipStream_t stream) {
    const float* pd  = (const float*)d_in[0];
    const float* gt  = (const float*)d_in[1];
    const int*   pdm = (const int*)d_in[2];
    const int*   gtm = (const int*)d_in[3];
    float* out = (float*)d_out;
    float2* ws = (float2*)d_ws;   // PAIRS * CPB float2 = 128 KB

    iou_partial_kernel<<<NBLK, 256, 0, stream>>>(pd, gt, pdm, gtm, ws);
    iou_final_kernel<<<1, 512, 0, stream>>>(ws, out);
}

// Round 6
// 68.241 us; speedup vs baseline: 1.2129x; 1.2129x over previous
//
#include <hip/hip_runtime.h>

// Geometry fixed by setup_inputs: b=16, n=32, h=w=256.
#define B 16
#define N 32
#define HW 65536
#define CHUNK 2048            // (h,w) elements per block
#define CPB (HW / CHUNK)      // 32 chunks per b
#define NG 8                  // n-values per block (acc budget: 16 VGPR)
#define NGRP (N / NG)         // 4 n-groups
#define NBLK (B * CPB * NGRP) // 2048 blocks
#define PAIRS (B * N)         // 512
#define F4 (CHUNK / 4 / 256)  // float4 per thread per stream = 2
#define EPS 1e-6f

// Lessons baked in:
//  R2/R3: NO cross-workgroup atomics/fences (per-block acq/rel = chip L2 flush).
//  R5:    register budget is the binding constraint on MLP — NG=8 not 32,
//         double- (not triple-) buffered masks, target <=128 VGPR.

__global__ __launch_bounds__(256, 4) void iou_partial_kernel(
    const float* __restrict__ pd, const float* __restrict__ gt,
    const int* __restrict__ pdm, const int* __restrict__ gtm,
    float2* __restrict__ ws)
{
    const int blk   = blockIdx.x;           // 0..2047
    const int ng    = blk & (NGRP - 1);     // n-group (fastest)
    const int chunk = (blk >> 2) & (CPB - 1);
    const int b     = blk >> 7;             // / (NGRP*CPB)
    const int t     = threadIdx.x;
    const int base  = chunk * CHUNK;

    const float4* __restrict__ pdp = (const float4*)(pd + (size_t)b * HW + base);
    const float4* __restrict__ gtp = (const float4*)(gt + (size_t)b * HW + base);
    const size_t mbase = (size_t)(b * N + ng * NG) * HW + base;
    const int4* __restrict__ pmp = (const int4*)(pdm + mbase);
    const int4* __restrict__ gmp = (const int4*)(gtm + mbase);

    // pd/gt chunk -> registers once for all NG masks (16 VGPR)
    float4 p[F4], g[F4];
    #pragma unroll
    for (int u = 0; u < F4; ++u) {
        p[u] = pdp[u * 256 + t];
        g[u] = gtp[u * 256 + t];
    }

    float accI[NG], accU[NG];
    int4 pmb[2][F4], gmb[2][F4];   // double buffer (32 VGPR)

#define LOADM(slot, n) { const int _o = (n) * (HW / 4);          \
    _Pragma("unroll") for (int u = 0; u < F4; ++u) {             \
        pmb[slot][u] = pmp[_o + u * 256 + t];                    \
        gmb[slot][u] = gmp[_o + u * 256 + t]; } }

    LOADM(0, 0)
    #pragma unroll
    for (int n = 0; n < NG; ++n) {          // fully unrolled: static indices only
        if (n + 1 < NG) LOADM((n + 1) & 1, n + 1)   // prefetch next n
        const int cur = n & 1;
        float I = 0.0f, U = 0.0f;
        #pragma unroll
        for (int u = 0; u < F4; ++u) {
            const int4 pm = pmb[cur][u];
            const int4 gm = gmb[cur][u];
            I += (pm.x & gm.x) ? p[u].x : 0.0f;
            I += (pm.y & gm.y) ? p[u].y : 0.0f;
            I += (pm.z & gm.z) ? p[u].z : 0.0f;
            I += (pm.w & gm.w) ? p[u].w : 0.0f;
            // union: exclusive paths -> nested select (2 cndmask)
            U += gm.x ? g[u].x : (pm.x ? p[u].x : 0.0f);
            U += gm.y ? g[u].y : (pm.y ? p[u].y : 0.0f);
            U += gm.z ? g[u].z : (pm.z ? p[u].z : 0.0f);
            U += gm.w ? g[u].w : (pm.w ? p[u].w : 0.0f);
        }
        accI[n] = I;
        accU[n] = U;
    }
#undef LOADM

    // per-n wave64 butterfly, then cross-wave via LDS
    __shared__ float sI[4][NG], sU[4][NG];
    const int wave = t >> 6, lane = t & 63;
    #pragma unroll
    for (int n = 0; n < NG; ++n) {
        float I = accI[n], U = accU[n];
        #pragma unroll
        for (int o = 32; o > 0; o >>= 1) {
            I += __shfl_down(I, o, 64);
            U += __shfl_down(U, o, 64);
        }
        if (lane == 0) { sI[wave][n] = I; sU[wave][n] = U; }
    }
    __syncthreads();
    if (t < NG) {
        const float I = sI[0][t] + sI[1][t] + sI[2][t] + sI[3][t];
        const float U = sU[0][t] + sU[1][t] + sU[2][t] + sU[3][t];
        const int pair = b * N + ng * NG + t;
        ws[(size_t)pair * CPB + chunk] = make_float2(I, U);
    }
}

__global__ __launch_bounds__(512) void iou_final_kernel(
    const float2* __restrict__ ws, float* __restrict__ out)
{
    const int t = threadIdx.x;   // one thread per (b,n) pair
    const float4* __restrict__ w4 = (const float4*)(ws + (size_t)t * CPB);
    float I = 0.0f, U = 0.0f;
    #pragma unroll
    for (int c = 0; c < CPB / 2; ++c) {   // CPB float2 = CPB/2 float4
        const float4 v = w4[c];
        I += v.x + v.z;
        U += v.y + v.w;
    }
    float loss = I / (U + EPS);

    #pragma unroll
    for (int o = 32; o > 0; o >>= 1)
        loss += __shfl_down(loss, o, 64);

    __shared__ float s[8];
    const int wave = t >> 6, lane = t & 63;
    if (lane == 0) s[wave] = loss;
    __syncthreads();
    if (t == 0) {
        float sum = 0.0f;
        #pragma unroll
        for (int w = 0; w < 8; ++w) sum += s[w];
        out[0] = 1.0f - sum / (float)PAIRS;
    }
}

extern "C" void kernel_launch(void* const* d_in, const int* in_sizes, int n_in,
                              void* d_out, int out_size, void* d_ws, size_t ws_size,
                              hipStream_t stream) {
    const float* pd  = (const float*)d_in[0];
    const float* gt  = (const float*)d_in[1];
    const int*   pdm = (const int*)d_in[2];
    const int*   gtm = (const int*)d_in[3];
    float* out = (float*)d_out;
    float2* ws = (float2*)d_ws;   // PAIRS * CPB float2 = 128 KB

    iou_partial_kernel<<<NBLK, 256, 0, stream>>>(pd, gt, pdm, gtm, ws);
    iou_final_kernel<<<1, 512, 0, stream>>>(ws, out);
}

// Round 7
// 56.051 us; speedup vs baseline: 1.4766x; 1.2175x over previous
//
#include <hip/hip_runtime.h>

// Geometry fixed by setup_inputs: b=16, n=32, h=w=256.
#define B 16
#define N 32
#define HW 65536
#define CHUNK 1024            // (h,w) elements per block
#define CPB (HW / CHUNK)      // 64 chunks per b
#define NG 8                  // n-values per block
#define NGRP (N / NG)         // 4 n-groups
#define NBLK (B * CPB * NGRP) // 4096 blocks
#define PAIRS (B * N)         // 512
#define EPS 1e-6f

// Lessons:
//  R2/R3: NO cross-workgroup atomics/fences (per-block acq/rel = chip L2 flush).
//  R5/R6: compiler targets 64-VGPR occupancy tier and will SPILL to get there —
//         keep true register need under ~56. F4=1, no manual multi-buffering.
//  R4/R6: XCD-chunked swizzle is required when blocks share pd/gt (else 3-4x
//         redundant pd/gt HBM fetch across XCD L2s).

__global__ __launch_bounds__(256, 4) void iou_partial_kernel(
    const float* __restrict__ pd, const float* __restrict__ gt,
    const int* __restrict__ pdm, const int* __restrict__ gtm,
    float2* __restrict__ ws)
{
    // Bijective XCD-chunked swizzle (NBLK % 8 == 0): hw block i (XCD i%8) ->
    // orig (i%8)*(NBLK/8) + i/8. Each XCD owns a contiguous 512-block range
    // = 2 b-values -> 1 MB pd/gt resident in its L2; masks stream.
    const int blk   = (blockIdx.x & 7) * (NBLK / 8) + (blockIdx.x >> 3);
    const int ng    = blk & (NGRP - 1);          // fastest: blocks sharing
    const int chunk = (blk >> 2) & (CPB - 1);    //   (b,chunk) are adjacent
    const int b     = blk >> 8;                  // / (NGRP*CPB)
    const int t     = threadIdx.x;
    const int base  = chunk * CHUNK;

    const float4* __restrict__ pdp = (const float4*)(pd + (size_t)b * HW + base);
    const float4* __restrict__ gtp = (const float4*)(gt + (size_t)b * HW + base);
    const size_t mbase = (size_t)(b * N + ng * NG) * HW + base;
    const int4* __restrict__ pmp = (const int4*)(pdm + mbase);
    const int4* __restrict__ gmp = (const int4*)(gtm + mbase);

    // pd/gt chunk -> 8 VGPR, loaded once for all NG masks
    const float4 p = pdp[t];
    const float4 g = gtp[t];

    float accI[NG], accU[NG];

    #pragma unroll
    for (int n = 0; n < NG; ++n) {               // static indices after unroll
        const int o = n * (HW / 4);
        const int4 pm = pmp[o + t];
        const int4 gm = gmp[o + t];
        float I = 0.0f, U = 0.0f;
        I += (pm.x & gm.x) ? p.x : 0.0f;
        I += (pm.y & gm.y) ? p.y : 0.0f;
        I += (pm.z & gm.z) ? p.z : 0.0f;
        I += (pm.w & gm.w) ? p.w : 0.0f;
        // union: exclusive paths -> nested select
        U += gm.x ? g.x : (pm.x ? p.x : 0.0f);
        U += gm.y ? g.y : (pm.y ? p.y : 0.0f);
        U += gm.z ? g.z : (pm.z ? p.z : 0.0f);
        U += gm.w ? g.w : (pm.w ? p.w : 0.0f);
        accI[n] = I;
        accU[n] = U;
    }

    // per-n wave64 butterfly, then cross-wave via LDS
    __shared__ float sI[4][NG], sU[4][NG];
    const int wave = t >> 6, lane = t & 63;
    #pragma unroll
    for (int n = 0; n < NG; ++n) {
        float I = accI[n], U = accU[n];
        #pragma unroll
        for (int o = 32; o > 0; o >>= 1) {
            I += __shfl_down(I, o, 64);
            U += __shfl_down(U, o, 64);
        }
        if (lane == 0) { sI[wave][n] = I; sU[wave][n] = U; }
    }
    __syncthreads();
    if (t < NG) {
        const float I = sI[0][t] + sI[1][t] + sI[2][t] + sI[3][t];
        const float U = sU[0][t] + sU[1][t] + sU[2][t] + sU[3][t];
        const int pair = b * N + ng * NG + t;
        ws[(size_t)pair * CPB + chunk] = make_float2(I, U);
    }
}

__global__ __launch_bounds__(512) void iou_final_kernel(
    const float2* __restrict__ ws, float* __restrict__ out)
{
    const int t = threadIdx.x;   // one thread per (b,n) pair
    const float4* __restrict__ w4 = (const float4*)(ws + (size_t)t * CPB);
    float I = 0.0f, U = 0.0f;
    #pragma unroll
    for (int c = 0; c < CPB / 2; ++c) {   // CPB float2 = CPB/2 float4
        const float4 v = w4[c];
        I += v.x + v.z;
        U += v.y + v.w;
    }
    float loss = I / (U + EPS);

    #pragma unroll
    for (int o = 32; o > 0; o >>= 1)
        loss += __shfl_down(loss, o, 64);

    __shared__ float s[8];
    const int wave = t >> 6, lane = t & 63;
    if (lane == 0) s[wave] = loss;
    __syncthreads();
    if (t == 0) {
        float sum = 0.0f;
        #pragma unroll
        for (int w = 0; w < 8; ++w) sum += s[w];
        out[0] = 1.0f - sum / (float)PAIRS;
    }
}

extern "C" void kernel_launch(void* const* d_in, const int* in_sizes, int n_in,
                              void* d_out, int out_size, void* d_ws, size_t ws_size,
                              hipStream_t stream) {
    const float* pd  = (const float*)d_in[0];
    const float* gt  = (const float*)d_in[1];
    const int*   pdm = (const int*)d_in[2];
    const int*   gtm = (const int*)d_in[3];
    float* out = (float*)d_out;
    float2* ws = (float2*)d_ws;   // PAIRS * CPB float2 = 256 KB

    iou_partial_kernel<<<NBLK, 256, 0, stream>>>(pd, gt, pdm, gtm, ws);
    iou_final_kernel<<<1, 512, 0, stream>>>(ws, out);
}

// Round 8
// 49.536 us; speedup vs baseline: 1.6709x; 1.1315x over previous
//
#include <hip/hip_runtime.h>

// Geometry fixed by setup_inputs: b=16, n=32, h=w=256.
#define B 16
#define N 32
#define HW 65536
#define CHUNK 1024            // elements per chunk-iteration (F4=1 per stream)
#define CI 4                  // chunk-iterations per block
#define CPB (HW / CHUNK)      // 64 chunks per b
#define CPG (CPB / CI)        // 16 chunk-groups per b
#define NG 8                  // n-values per block
#define NGRP (N / NG)         // 4 n-groups
#define NBLK (B * CPG * NGRP) // 1024 blocks
#define PAIRS (B * N)         // 512
#define EPS 1e-6f

// Lessons:
//  R2/R3: NO cross-workgroup atomics/fences (per-block acq/rel = chip L2 flush).
//  R5/R6: keep true VGPR need < ~56 (compiler spills to hit the 64 tier).
//  R4/R6: XCD-chunked swizzle required where blocks share pd/gt.
//  R7:    ws must be [chunk][pair] so the final kernel reads coalesced;
//         reduce once per block (LDS transpose), not once per tiny chunk.

__global__ __launch_bounds__(256, 4) void iou_partial_kernel(
    const float* __restrict__ pd, const float* __restrict__ gt,
    const int* __restrict__ pdm, const int* __restrict__ gtm,
    float2* __restrict__ ws)
{
    // Bijective XCD-chunked swizzle (NBLK=1024, /8=128): each XCD owns a
    // contiguous 128-origblock range = 2 b-values -> 1 MB pd/gt L2-resident.
    const int blk = (blockIdx.x & 7) * (NBLK / 8) + (blockIdx.x >> 3);
    const int ng  = blk & (NGRP - 1);
    const int cg  = (blk >> 2) & (CPG - 1);
    const int b   = blk >> 6;            // / (NGRP*CPG)
    const int t   = threadIdx.x;
    const int base = cg * (CHUNK * CI);  // element offset into (h,w)

    const float4* __restrict__ pdp = (const float4*)(pd + (size_t)b * HW + base);
    const float4* __restrict__ gtp = (const float4*)(gt + (size_t)b * HW + base);
    const size_t mbase = (size_t)(b * N + ng * NG) * HW + base;
    const int4* __restrict__ pmp = (const int4*)(pdm + mbase);
    const int4* __restrict__ gmp = (const int4*)(gtm + mbase);

    float accI[NG] = {0,0,0,0,0,0,0,0};
    float accU[NG] = {0,0,0,0,0,0,0,0};

    #pragma unroll 1    // do NOT unroll: keeps live loads ~18, VGPR ~40 (R5/R6)
    for (int ci = 0; ci < CI; ++ci) {
        const int idx = ci * (CHUNK / 4) + t;
        const float4 p = pdp[idx];
        const float4 g = gtp[idx];
        #pragma unroll  // static n -> acc stays in registers
        for (int n = 0; n < NG; ++n) {
            const int4 pm = pmp[n * (HW / 4) + idx];
            const int4 gm = gmp[n * (HW / 4) + idx];
            float I = 0.0f, U = 0.0f;
            I += (pm.x & gm.x) ? p.x : 0.0f;
            I += (pm.y & gm.y) ? p.y : 0.0f;
            I += (pm.z & gm.z) ? p.z : 0.0f;
            I += (pm.w & gm.w) ? p.w : 0.0f;
            U += gm.x ? g.x : (pm.x ? p.x : 0.0f);
            U += gm.y ? g.y : (pm.y ? p.y : 0.0f);
            U += gm.z ? g.z : (pm.z ? p.z : 0.0f);
            U += gm.w ? g.w : (pm.w ? p.w : 0.0f);
            accI[n] += I;
            accU[n] += U;
        }
    }

    // One block-level reduction: LDS transpose, then 32-lane-group reduce.
    __shared__ float sI[NG][256], sU[NG][256];
    #pragma unroll
    for (int n = 0; n < NG; ++n) { sI[n][t] = accI[n]; sU[n][t] = accU[n]; }
    __syncthreads();

    const int g8 = t >> 5;   // n handled by this 32-thread group
    const int l  = t & 31;
    float I = 0.0f, U = 0.0f;
    #pragma unroll
    for (int k = 0; k < 8; ++k) {   // 256 entries / 32 lanes
        I += sI[g8][l + 32 * k];
        U += sU[g8][l + 32 * k];
    }
    #pragma unroll
    for (int m = 16; m > 0; m >>= 1) {   // stays within 32-lane halves
        I += __shfl_xor(I, m, 64);
        U += __shfl_xor(U, m, 64);
    }
    if (l == 0) {
        const int pair = b * N + ng * NG + g8;
        ws[(size_t)cg * PAIRS + pair] = make_float2(I, U);
    }
}

__global__ __launch_bounds__(256) void iou_final_kernel(
    const float2* __restrict__ ws, float* __restrict__ out)
{
    const int t = threadIdx.x;   // thread t handles pairs 2t, 2t+1
    const float4* __restrict__ w4 = (const float4*)ws;  // [CPG][PAIRS/2] float4
    float I0 = 0.0f, U0 = 0.0f, I1 = 0.0f, U1 = 0.0f;
    #pragma unroll
    for (int cg = 0; cg < CPG; ++cg) {
        const float4 v = w4[cg * (PAIRS / 2) + t];   // coalesced
        I0 += v.x; U0 += v.y;
        I1 += v.z; U1 += v.w;
    }
    float loss = I0 / (U0 + EPS) + I1 / (U1 + EPS);

    #pragma unroll
    for (int o = 32; o > 0; o >>= 1)
        loss += __shfl_down(loss, o, 64);

    __shared__ float s[4];
    const int wave = t >> 6, lane = t & 63;
    if (lane == 0) s[wave] = loss;
    __syncthreads();
    if (t == 0)
        out[0] = 1.0f - (s[0] + s[1] + s[2] + s[3]) / (float)PAIRS;
}

extern "C" void kernel_launch(void* const* d_in, const int* in_sizes, int n_in,
                              void* d_out, int out_size, void* d_ws, size_t ws_size,
                              hipStream_t stream) {
    const float* pd  = (const float*)d_in[0];
    const float* gt  = (const float*)d_in[1];
    const int*   pdm = (const int*)d_in[2];
    const int*   gtm = (const int*)d_in[3];
    float* out = (float*)d_out;
    float2* ws = (float2*)d_ws;   // CPG * PAIRS float2 = 64 KB

    iou_partial_kernel<<<NBLK, 256, 0, stream>>>(pd, gt, pdm, gtm, ws);
    iou_final_kernel<<<1, 256, 0, stream>>>(ws, out);
}

// Round 9
// 46.756 us; speedup vs baseline: 1.7702x; 1.0595x over previous
//
#include <hip/hip_runtime.h>

// Geometry fixed by setup_inputs: b=16, n=32, h=w=256.
#define B 16
#define N 32
#define HW 65536            // 256*256
#define CHUNKS 4            // chunks per (b,n) pair
#define CHUNK (HW / CHUNKS) // 16384 elements per block
#define PAIRS (B * N)       // 512
#define NBLK (PAIRS * CHUNKS) // 2048
#define EPS 1e-6f

// Converged structure (R4 = 46.4us = ~90% of the 6.3 TB/s fabric ceiling on
// 264 MB irreducible traffic). Lessons:
//  R2/R3: NO cross-workgroup atomics/fences (per-block acq/rel = chip L2 flush).
//  R5/R6: keep true VGPR need < ~56 or the compiler spills chasing occupancy.
//  R4/R6: XCD-chunked swizzle required where blocks share pd/gt.
//  R8:    halving VMEM instruction count did NOT help -> fabric-byte-bound,
//         not VMEM-issue-bound. 264 MB must cross the fabric; floor ~42us.

__global__ __launch_bounds__(256, 4) void iou_partial_kernel(
    const float* __restrict__ pd, const float* __restrict__ gt,
    const int* __restrict__ pdm, const int* __restrict__ gtm,
    float2* __restrict__ ws)
{
    // Bijective XCD-chunked swizzle (NBLK=2048): hw block i (XCD i%8) ->
    // orig (i%8)*256 + i/8; each XCD owns 2 b-values -> pd/gt L2-resident.
    const int blk   = (blockIdx.x & 7) * (NBLK / 8) + (blockIdx.x >> 3);
    const int pair  = blk >> 2;          // b*N + n
    const int chunk = blk & 3;
    const int b     = pair >> 5;
    const int t     = threadIdx.x;

    const int base = chunk * CHUNK;
    const float4* __restrict__ pdp = (const float4*)(pd + (size_t)b * HW + base);
    const float4* __restrict__ gtp = (const float4*)(gt + (size_t)b * HW + base);
    const int4*   __restrict__ pmp = (const int4*)(pdm + (size_t)pair * HW + base);
    const int4*   __restrict__ gmp = (const int4*)(gtm + (size_t)pair * HW + base);

    float inter = 0.0f, uni = 0.0f;

    // CHUNK/4 = 4096 float4 per stream, 256 threads -> 16 iters/thread,
    // batch-4 interleave (16 x 16B loads in flight, then consume).
    #pragma unroll
    for (int o = 0; o < 4; ++o) {
        float4 p[4], g[4];
        int4  pm[4], gm[4];
        #pragma unroll
        for (int u = 0; u < 4; ++u) {
            const int i = (o * 4 + u) * 256 + t;
            pm[u] = pmp[i];
            gm[u] = gmp[i];
            p[u]  = pdp[i];
            g[u]  = gtp[i];
        }
        #pragma unroll
        for (int u = 0; u < 4; ++u) {
            inter += (pm[u].x & gm[u].x) ? p[u].x : 0.0f;
            inter += (pm[u].y & gm[u].y) ? p[u].y : 0.0f;
            inter += (pm[u].z & gm[u].z) ? p[u].z : 0.0f;
            inter += (pm[u].w & gm[u].w) ? p[u].w : 0.0f;

            uni += (gm[u].x ? g[u].x : 0.0f) + ((pm[u].x & ~gm[u].x) ? p[u].x : 0.0f);
            uni += (gm[u].y ? g[u].y : 0.0f) + ((pm[u].y & ~gm[u].y) ? p[u].y : 0.0f);
            uni += (gm[u].z ? g[u].z : 0.0f) + ((pm[u].z & ~gm[u].z) ? p[u].z : 0.0f);
            uni += (gm[u].w ? g[u].w : 0.0f) + ((pm[u].w & ~gm[u].w) ? p[u].w : 0.0f);
        }
    }

    #pragma unroll
    for (int o = 32; o > 0; o >>= 1) {
        inter += __shfl_down(inter, o, 64);
        uni   += __shfl_down(uni, o, 64);
    }

    __shared__ float s_i[4], s_u[4];
    const int wave = t >> 6, lane = t & 63;
    if (lane == 0) { s_i[wave] = inter; s_u[wave] = uni; }
    __syncthreads();
    if (t == 0) {
        ws[blk] = make_float2(s_i[0] + s_i[1] + s_i[2] + s_i[3],
                              s_u[0] + s_u[1] + s_u[2] + s_u[3]);
    }
}

__global__ __launch_bounds__(512) void iou_final_kernel(
    const float2* __restrict__ ws, float* __restrict__ out)
{
    const int t = threadIdx.x;   // one thread per (b,n) pair
    // ws[pair*4 + c] -> two contiguous float4 per thread (coalesced 32B/lane)
    const float4* __restrict__ w4 = (const float4*)(ws + (size_t)t * CHUNKS);
    const float4 v0 = w4[0];
    const float4 v1 = w4[1];
    const float I = v0.x + v0.z + v1.x + v1.z;
    const float U = v0.y + v0.w + v1.y + v1.w;
    float loss = I / (U + EPS);

    #pragma unroll
    for (int o = 32; o > 0; o >>= 1)
        loss += __shfl_down(loss, o, 64);

    __shared__ float s[8];
    const int wave = t >> 6, lane = t & 63;
    if (lane == 0) s[wave] = loss;
    __syncthreads();
    if (t == 0) {
        float sum = 0.0f;
        #pragma unroll
        for (int w = 0; w < 8; ++w) sum += s[w];
        out[0] = 1.0f - sum / (float)PAIRS;
    }
}

extern "C" void kernel_launch(void* const* d_in, const int* in_sizes, int n_in,
                              void* d_out, int out_size, void* d_ws, size_t ws_size,
                              hipStream_t stream) {
    const float* pd  = (const float*)d_in[0];
    const float* gt  = (const float*)d_in[1];
    const int*   pdm = (const int*)d_in[2];
    const int*   gtm = (const int*)d_in[3];
    float* out = (float*)d_out;
    float2* ws = (float2*)d_ws;   // NBLK float2 = 16 KB

    iou_partial_kernel<<<NBLK, 256, 0, stream>>>(pd, gt, pdm, gtm, ws);
    iou_final_kernel<<<1, 512, 0, stream>>>(ws, out);
}